// Round 10
// baseline (2719.788 us; speedup 1.0000x reference)
//
#include <hip/hip_runtime.h>
#include <hip/hip_bf16.h>

#define N_ 8192
#define T_ 12
#define B_ 2
#define FIN_ 8
#define HID_ 16
#define CGSZ 131072   // one column-group (16 cols) frag block: 256 kb * 64 lanes * 8 elems

typedef short s8v __attribute__((ext_vector_type(8)));
typedef float f4v __attribute__((ext_vector_type(4)));

__device__ __forceinline__ float sigmoidf_(float x){ return 1.f/(1.f + __expf(-x)); }

// ---------------- prep: L fp32 -> bf16 fragment-major ----------------
// Lp[((rt*256 + kb)*64 + l)*8 + e] = bf16( L[rt*16 + (l&15)][kb*32 + (l>>4)*8 + e] )
__global__ __launch_bounds__(256) void build_Lp_kernel(const float* __restrict__ L,
                                                       __hip_bfloat16* __restrict__ Lp){
  __shared__ unsigned short tile[16][264];
  const int cb = blockIdx.x;   // 0..31
  const int rt = blockIdx.y;   // 0..511
  const int tid = threadIdx.x;
  #pragma unroll
  for (int i = 0; i < 4; ++i){
    int flat = i*256 + tid;
    int r  = flat >> 6;
    int c4 = flat & 63;
    float4 v = *(const float4*)(L + (long)(rt*16 + r)*N_ + cb*256 + c4*4);
    tile[r][c4*4+0] = __bfloat16_as_ushort(__float2bfloat16(v.x));
    tile[r][c4*4+1] = __bfloat16_as_ushort(__float2bfloat16(v.y));
    tile[r][c4*4+2] = __bfloat16_as_ushort(__float2bfloat16(v.z));
    tile[r][c4*4+3] = __bfloat16_as_ushort(__float2bfloat16(v.w));
  }
  __syncthreads();
  #pragma unroll
  for (int j = 0; j < 2; ++j){
    int flat = j*256 + tid;
    int kbl = flat >> 6;
    int l   = flat & 63;
    int lid = l & 15, g = l >> 4;
    uint4 frag = *(const uint4*)&tile[lid][kbl*32 + g*8];
    *(uint4*)(Lp + (((long)rt*256 + cb*8 + kbl)*64 + l)*8) = frag;
  }
}

// ---------------- prep: X (all t) and h0 -> bf16 frag-major (merged) ----------------
__global__ __launch_bounds__(256) void pack_xh_kernel(const float* __restrict__ X,
                                                      const float* __restrict__ H,
                                                      __hip_bfloat16* __restrict__ XTf,
                                                      __hip_bfloat16* __restrict__ hTf){
  if (blockIdx.x < 768){
    const int t = blockIdx.x >> 6;
    int flat = (blockIdx.x & 63)*256 + threadIdx.x;   // 0..16383
    int l = flat & 63, kb = flat >> 6;
    int lid = l & 15, g = l >> 4;
    int b = lid >> 3, f = lid & 7;
    int n0 = kb*32 + g*8;
    unsigned short u[8];
    #pragma unroll
    for (int e = 0; e < 8; ++e)
      u[e] = __bfloat16_as_ushort(__float2bfloat16(
          X[(((long)(b*T_ + t))*N_ + n0 + e)*FIN_ + f]));
    *(uint4*)(XTf + ((long)t*CGSZ + ((long)kb*64 + l)*8)) = *(uint4*)u;
  } else {
    int flat = (blockIdx.x - 768)*256 + threadIdx.x;  // 0..32767
    int l = flat & 63, kb = (flat >> 6) & 255, b = flat >> 14;
    int lid = l & 15, g = l >> 4;
    int n0 = kb*32 + g*8;
    unsigned short u[8];
    #pragma unroll
    for (int e = 0; e < 8; ++e)
      u[e] = __bfloat16_as_ushort(__float2bfloat16(
          H[((long)b*N_ + n0 + e)*HID_ + lid]));
    *(uint4*)(hTf + ((long)b*CGSZ + ((long)kb*64 + l)*8)) = *(uint4*)u;
  }
}

// ---------------- MFMA core (baseline, unroll 4, normal loads) ----------------
__device__ __forceinline__ void mm_core32(
    const __hip_bfloat16* __restrict__ Lp,
    const __hip_bfloat16* __restrict__ B0f,
    const __hip_bfloat16* __restrict__ B1f,
    const __hip_bfloat16* __restrict__ B2f,
    float (*red)[2][3][64][4], int blk, int w, int lane)
{
  const int kb0 = w*32;
  const s8v* A0 = (const s8v*)(const void*)Lp + ((long)(blk*2+0)*256 + kb0)*64 + lane;
  const s8v* A1 = (const s8v*)(const void*)Lp + ((long)(blk*2+1)*256 + kb0)*64 + lane;
  const s8v* P0 = (const s8v*)(const void*)B0f + (long)kb0*64 + lane;
  const s8v* P1 = (const s8v*)(const void*)B1f + (long)kb0*64 + lane;
  const s8v* P2 = (const s8v*)(const void*)B2f + (long)kb0*64 + lane;
  f4v a00={0.f,0.f,0.f,0.f}, a01={0.f,0.f,0.f,0.f}, a02={0.f,0.f,0.f,0.f};
  f4v a10={0.f,0.f,0.f,0.f}, a11={0.f,0.f,0.f,0.f}, a12={0.f,0.f,0.f,0.f};
  #pragma unroll 4
  for (int kk = 0; kk < 32; ++kk){
    s8v a0 = A0[(long)kk*64];
    s8v a1 = A1[(long)kk*64];
    s8v b0 = P0[(long)kk*64];
    s8v b1 = P1[(long)kk*64];
    s8v b2 = P2[(long)kk*64];
    a00 = __builtin_amdgcn_mfma_f32_16x16x32_bf16(a0,b0,a00,0,0,0);
    a01 = __builtin_amdgcn_mfma_f32_16x16x32_bf16(a0,b1,a01,0,0,0);
    a02 = __builtin_amdgcn_mfma_f32_16x16x32_bf16(a0,b2,a02,0,0,0);
    a10 = __builtin_amdgcn_mfma_f32_16x16x32_bf16(a1,b0,a10,0,0,0);
    a11 = __builtin_amdgcn_mfma_f32_16x16x32_bf16(a1,b1,a11,0,0,0);
    a12 = __builtin_amdgcn_mfma_f32_16x16x32_bf16(a1,b2,a12,0,0,0);
  }
  *(f4v*)&red[w][0][0][lane][0] = a00;
  *(f4v*)&red[w][0][1][lane][0] = a01;
  *(f4v*)&red[w][0][2][lane][0] = a02;
  *(f4v*)&red[w][1][0][lane][0] = a10;
  *(f4v*)&red[w][1][1][lane][0] = a11;
  *(f4v*)&red[w][1][2][lane][0] = a12;
}

// ---------------- MFMA core variant: nontemporal A ONLY (unroll 4 kept) ----------------
__device__ __forceinline__ void mm_core32_nt(
    const __hip_bfloat16* __restrict__ Lp,
    const __hip_bfloat16* __restrict__ B0f,
    const __hip_bfloat16* __restrict__ B1f,
    const __hip_bfloat16* __restrict__ B2f,
    float (*red)[2][3][64][4], int blk, int w, int lane)
{
  const int kb0 = w*32;
  const s8v* A0 = (const s8v*)(const void*)Lp + ((long)(blk*2+0)*256 + kb0)*64 + lane;
  const s8v* A1 = (const s8v*)(const void*)Lp + ((long)(blk*2+1)*256 + kb0)*64 + lane;
  const s8v* P0 = (const s8v*)(const void*)B0f + (long)kb0*64 + lane;
  const s8v* P1 = (const s8v*)(const void*)B1f + (long)kb0*64 + lane;
  const s8v* P2 = (const s8v*)(const void*)B2f + (long)kb0*64 + lane;
  f4v a00={0.f,0.f,0.f,0.f}, a01={0.f,0.f,0.f,0.f}, a02={0.f,0.f,0.f,0.f};
  f4v a10={0.f,0.f,0.f,0.f}, a11={0.f,0.f,0.f,0.f}, a12={0.f,0.f,0.f,0.f};
  #pragma unroll 4
  for (int kk = 0; kk < 32; ++kk){
    s8v a0 = __builtin_nontemporal_load(A0 + (long)kk*64);
    s8v a1 = __builtin_nontemporal_load(A1 + (long)kk*64);
    s8v b0 = P0[(long)kk*64];
    s8v b1 = P1[(long)kk*64];
    s8v b2 = P2[(long)kk*64];
    a00 = __builtin_amdgcn_mfma_f32_16x16x32_bf16(a0,b0,a00,0,0,0);
    a01 = __builtin_amdgcn_mfma_f32_16x16x32_bf16(a0,b1,a01,0,0,0);
    a02 = __builtin_amdgcn_mfma_f32_16x16x32_bf16(a0,b2,a02,0,0,0);
    a10 = __builtin_amdgcn_mfma_f32_16x16x32_bf16(a1,b0,a10,0,0,0);
    a11 = __builtin_amdgcn_mfma_f32_16x16x32_bf16(a1,b1,a11,0,0,0);
    a12 = __builtin_amdgcn_mfma_f32_16x16x32_bf16(a1,b2,a12,0,0,0);
  }
  *(f4v*)&red[w][0][0][lane][0] = a00;
  *(f4v*)&red[w][0][1][lane][0] = a01;
  *(f4v*)&red[w][0][2][lane][0] = a02;
  *(f4v*)&red[w][1][0][lane][0] = a10;
  *(f4v*)&red[w][1][1][lane][0] = a11;
  *(f4v*)&red[w][1][2][lane][0] = a12;
}

// ---------------- pass 1: [u(32) | p(16)] = L @ [h | x_t]  (+ bf16 frag out) ----------------
// rep > 1 re-executes the identical (idempotent) body -- measurement aid so this
// kernel rises into rocprof's top-k; outputs byte-identical for any rep.
__global__ __launch_bounds__(512) void mm_pass1_kernel(
    const __hip_bfloat16* __restrict__ Lp,
    const __hip_bfloat16* __restrict__ hTf,
    const __hip_bfloat16* __restrict__ XTft,
    __hip_bfloat16* __restrict__ y1f,
    float* __restrict__ u_, float* __restrict__ p_, int rep)
{
  __shared__ float red[8][2][3][64][4];   // 49152 B
  const int tid = threadIdx.x, w = tid >> 6, lane = tid & 63, blk = blockIdx.x;
  for (int r0 = 0; r0 < rep; ++r0){
    mm_core32(Lp, hTf, hTf + CGSZ, XTft, red, blk, w, lane);
    __syncthreads();
    for (int v = tid; v < 1536; v += 512){
      int rtl = (v >= 768) ? 1 : 0;
      int rem = v - rtl*768;
      int cgI = rem >> 8, r255 = rem & 255;
      int lid = r255 & 15, r = r255 >> 4;
      int g = r >> 2, j = r & 3;
      float s = 0.f;
      #pragma unroll
      for (int ww = 0; ww < 8; ++ww) s += red[ww][rtl][cgI][g*16 + lid][j];
      int n = blk*32 + rtl*16 + r;
      long o = (((long)cgI*256 + (n>>5))*64 + ((n>>3)&3)*16 + lid)*8 + (n&7);
      y1f[o] = __float2bfloat16(s);
      if (cgI < 2) u_[((long)cgI*N_ + n)*HID_ + lid] = s;
      else         p_[((long)(lid>>3)*N_ + n)*FIN_ + (lid&7)] = s;
    }
    __syncthreads();
  }
}

// ---------------- pass 2 + fused gates (A/B variant: nontemporal-A core) ----------------
__global__ __launch_bounds__(512) void mm_pass2_gate_kernel(
    const __hip_bfloat16* __restrict__ Lp,
    const __hip_bfloat16* __restrict__ y1f,
    const float* __restrict__ X,
    const float* __restrict__ H0, const float* __restrict__ C0,
    const float* __restrict__ Wx, const float* __restrict__ Wh,
    const float* __restrict__ bx, const float* __restrict__ bh,
    const float* __restrict__ wc, const float* __restrict__ bg,
    const float* __restrict__ u_, const float* __restrict__ p_,
    float* __restrict__ out, float* __restrict__ hs, float* __restrict__ cs,
    __hip_bfloat16* __restrict__ hTf, int t)
{
  __shared__ float red[8][2][3][64][4];   // 49152 B
  __shared__ float uv[48][32];            //  6144 B  [col][row-in-block]
  __shared__ float wlds[4848];            // 19392 B
  const int tid = threadIdx.x, w = tid >> 6, lane = tid & 63, blk = blockIdx.x;
  mm_core32_nt(Lp, y1f, y1f + CGSZ, y1f + 2*CGSZ, red, blk, w, lane);
  // stage this timestep's gate weights (independent of red)
  for (int i = tid; i < 1536; i += 512) wlds[i] = Wx[(long)t*1536 + i];
  for (int i = tid; i < 3072; i += 512) wlds[1536 + i] = Wh[(long)t*3072 + i];
  if (tid < 64){
    wlds[4608 + tid] = bx[t*64 + tid];
    wlds[4672 + tid] = bh[t*64 + tid];
    wlds[4736 + tid] = bg[t*64 + tid];
  }
  if (tid < 48) wlds[4800 + tid] = wc[t*48 + tid];
  __syncthreads();
  for (int v = tid; v < 1536; v += 512){
    int rtl = (v >= 768) ? 1 : 0;
    int rem = v - rtl*768;
    int cgI = rem >> 8, r255 = rem & 255;
    int lid = r255 & 15, r = r255 >> 4;
    int g = r >> 2, j = r & 3;
    float s = 0.f;
    #pragma unroll
    for (int ww = 0; ww < 8; ++ww) s += red[ww][rtl][cgI][g*16 + lid][j];
    uv[cgI*16 + lid][rtl*16 + r] = s;
  }
  __syncthreads();

  // gates: 1024 items (2 batch x 32 rows x 16 hid) over 512 threads
  #pragma unroll
  for (int it = 0; it < 2; ++it){
    int item = it*512 + tid;
    int gb = item >> 9, rr = (item >> 4) & 31, gh = item & 15;
    int n_g = blk*32 + rr;
    const float* xp = X + (((long)(gb*T_ + t))*N_ + n_g)*FIN_;
    const float* hp = (t==0) ? (H0 + ((long)gb*N_ + n_g)*HID_)
                             : (hs + (((long)(t-1)*B_ + gb)*N_ + n_g)*HID_);
    const float* cp = (t==0) ? (C0 + ((long)gb*N_ + n_g)*HID_)
                             : (cs + (((long)(t-1)*B_ + gb)*N_ + n_g)*HID_);
    const float* up = u_ + ((long)gb*N_ + n_g)*HID_;
    const float* pp = p_ + ((long)gb*N_ + n_g)*FIN_;

    float pre0 = wlds[4608 +  0 + gh] + wlds[4672 +  0 + gh] + wlds[4736 +  0 + gh];
    float pre1 = wlds[4608 + 16 + gh] + wlds[4672 + 16 + gh] + wlds[4736 + 16 + gh];
    float pre2 = wlds[4608 + 32 + gh] + wlds[4672 + 32 + gh] + wlds[4736 + 32 + gh];
    float pre3 = wlds[4608 + 48 + gh] + wlds[4672 + 48 + gh] + wlds[4736 + 48 + gh];
    #pragma unroll
    for (int f = 0; f < 8; ++f){
      float t0 = xp[f];
      float t1 = pp[f];
      float t2 = 2.f*uv[32 + gb*8 + f][rr] - t0;
      pre0 += t0*wlds[((0*3+0)*8+f)*16+gh] + t1*wlds[((0*3+1)*8+f)*16+gh] + t2*wlds[((0*3+2)*8+f)*16+gh];
      pre1 += t0*wlds[((1*3+0)*8+f)*16+gh] + t1*wlds[((1*3+1)*8+f)*16+gh] + t2*wlds[((1*3+2)*8+f)*16+gh];
      pre2 += t0*wlds[((2*3+0)*8+f)*16+gh] + t1*wlds[((2*3+1)*8+f)*16+gh] + t2*wlds[((2*3+2)*8+f)*16+gh];
      pre3 += t0*wlds[((3*3+0)*8+f)*16+gh] + t1*wlds[((3*3+1)*8+f)*16+gh] + t2*wlds[((3*3+2)*8+f)*16+gh];
    }
    #pragma unroll
    for (int j = 0; j < 16; ++j){
      float t0 = hp[j];
      float t1 = up[j];
      float t2 = 2.f*uv[gb*16 + j][rr] - t0;
      pre0 += t0*wlds[1536+((0*3+0)*16+j)*16+gh] + t1*wlds[1536+((0*3+1)*16+j)*16+gh] + t2*wlds[1536+((0*3+2)*16+j)*16+gh];
      pre1 += t0*wlds[1536+((1*3+0)*16+j)*16+gh] + t1*wlds[1536+((1*3+1)*16+j)*16+gh] + t2*wlds[1536+((1*3+2)*16+j)*16+gh];
      pre2 += t0*wlds[1536+((2*3+0)*16+j)*16+gh] + t1*wlds[1536+((2*3+1)*16+j)*16+gh] + t2*wlds[1536+((2*3+2)*16+j)*16+gh];
      pre3 += t0*wlds[1536+((3*3+0)*16+j)*16+gh] + t1*wlds[1536+((3*3+1)*16+j)*16+gh] + t2*wlds[1536+((3*3+2)*16+j)*16+gh];
    }
    float cc = cp[gh];
    float ig = sigmoidf_(pre0 + wlds[4800 +  0 + gh]*cc);
    float fg = sigmoidf_(pre1 + wlds[4800 + 16 + gh]*cc);
    float cnew = fg*cc + ig*tanhf(pre2);
    float og = sigmoidf_(pre3 + wlds[4800 + 32 + gh]*cnew);
    float hn = og*tanhf(cnew);
    hs [(((long)t*B_ + gb)*N_ + n_g)*HID_ + gh] = hn;
    cs [(((long)t*B_ + gb)*N_ + n_g)*HID_ + gh] = cnew;
    out[(((long)gb*T_ + t)*N_ + n_g)*HID_ + gh] = hn;
    const int kb = n_g >> 5, gg = (n_g >> 3) & 3, e = n_g & 7;
    hTf[(((long)gb*256 + kb)*64 + gg*16 + gh)*8 + e] = __float2bfloat16(hn);
  }
}

extern "C" void kernel_launch(void* const* d_in, const int* in_sizes, int n_in,
                              void* d_out, int out_size, void* d_ws, size_t ws_size,
                              hipStream_t stream)
{
  const float* X  = (const float*)d_in[0];
  const float* L  = (const float*)d_in[1];
  const float* H  = (const float*)d_in[2];
  const float* C  = (const float*)d_in[3];
  const float* Wx = (const float*)d_in[4];
  const float* Wh = (const float*)d_in[5];
  const float* bx = (const float*)d_in[6];
  const float* bh = (const float*)d_in[7];
  const float* wc = (const float*)d_in[8];
  const float* bg = (const float*)d_in[9];

  float* out = (float*)d_out;
  float* hs  = out + (long)B_*T_*N_*HID_;
  float* cs  = hs  + (long)T_*B_*N_*HID_;

  const size_t NEEDED = 140247040;
  if (ws_size < NEEDED) return;
  char* ws = (char*)d_ws;
  __hip_bfloat16* Lp  = (__hip_bfloat16*)(ws);                   // 128 MiB frag-major L
  __hip_bfloat16* XTf = (__hip_bfloat16*)(ws + 134217728);       // 3 MiB   [12][CGSZ]
  __hip_bfloat16* hTf = (__hip_bfloat16*)(ws + 137363456);       // 512 KiB [2][CGSZ]
  __hip_bfloat16* y1f = (__hip_bfloat16*)(ws + 137887744);       // 768 KiB [3][CGSZ]
  float* u_ = (float*)(ws + 138674176);                          // 1 MiB   [2][8192][16]
  float* p_ = (float*)(ws + 139722752);                          // 512 KiB [2][8192][8]

  build_Lp_kernel<<<dim3(32,512), 256, 0, stream>>>(L, Lp);
  pack_xh_kernel <<<896, 256, 0, stream>>>(X, H, XTf, hTf);

  for (int t = 0; t < T_; ++t){
    // rep=6: measurement aid (idempotent) -- lifts pass1 above harness fillBuffer
    // dispatches (~150 us) so rocprof top-k finally shows the hot loop's counters.
    mm_pass1_kernel<<<256, 512, 0, stream>>>(Lp, hTf, XTf + (long)t*CGSZ,
                                             y1f, u_, p_, 6);
    // pass2 carries the A/B variant: nontemporal-A core (unroll 4 unchanged).
    mm_pass2_gate_kernel<<<256, 512, 0, stream>>>(Lp, y1f, X, H, C,
                                                  Wx, Wh, bx, bh, wc, bg,
                                                  u_, p_, out, hs, cs, hTf, t);
  }
}

// Round 11
// 1204.249 us; speedup vs baseline: 2.2585x; 2.2585x over previous
//
#include <hip/hip_runtime.h>
#include <hip/hip_bf16.h>

#define N_ 8192
#define T_ 12
#define B_ 2
#define FIN_ 8
#define HID_ 16
#define CGSZ 131072   // one column-group (16 cols) frag block: 256 kb * 64 lanes * 8 elems

typedef short s8v __attribute__((ext_vector_type(8)));
typedef float f4v __attribute__((ext_vector_type(4)));

__device__ __forceinline__ float sigmoidf_(float x){ return 1.f/(1.f + __expf(-x)); }

// ---------------- prep: L fp32 -> bf16 fragment-major ----------------
// Lp[((rt*256 + kb)*64 + l)*8 + e] = bf16( L[rt*16 + (l&15)][kb*32 + (l>>4)*8 + e] )
__global__ __launch_bounds__(256) void build_Lp_kernel(const float* __restrict__ L,
                                                       __hip_bfloat16* __restrict__ Lp){
  __shared__ unsigned short tile[16][264];
  const int cb = blockIdx.x;   // 0..31
  const int rt = blockIdx.y;   // 0..511
  const int tid = threadIdx.x;
  #pragma unroll
  for (int i = 0; i < 4; ++i){
    int flat = i*256 + tid;
    int r  = flat >> 6;
    int c4 = flat & 63;
    float4 v = *(const float4*)(L + (long)(rt*16 + r)*N_ + cb*256 + c4*4);
    tile[r][c4*4+0] = __bfloat16_as_ushort(__float2bfloat16(v.x));
    tile[r][c4*4+1] = __bfloat16_as_ushort(__float2bfloat16(v.y));
    tile[r][c4*4+2] = __bfloat16_as_ushort(__float2bfloat16(v.z));
    tile[r][c4*4+3] = __bfloat16_as_ushort(__float2bfloat16(v.w));
  }
  __syncthreads();
  #pragma unroll
  for (int j = 0; j < 2; ++j){
    int flat = j*256 + tid;
    int kbl = flat >> 6;
    int l   = flat & 63;
    int lid = l & 15, g = l >> 4;
    uint4 frag = *(const uint4*)&tile[lid][kbl*32 + g*8];
    *(uint4*)(Lp + (((long)rt*256 + cb*8 + kbl)*64 + l)*8) = frag;
  }
}

// ---------------- prep: X (all t) and h0 -> bf16 frag-major (merged) ----------------
__global__ __launch_bounds__(256) void pack_xh_kernel(const float* __restrict__ X,
                                                      const float* __restrict__ H,
                                                      __hip_bfloat16* __restrict__ XTf,
                                                      __hip_bfloat16* __restrict__ hTf){
  if (blockIdx.x < 768){
    const int t = blockIdx.x >> 6;
    int flat = (blockIdx.x & 63)*256 + threadIdx.x;   // 0..16383
    int l = flat & 63, kb = flat >> 6;
    int lid = l & 15, g = l >> 4;
    int b = lid >> 3, f = lid & 7;
    int n0 = kb*32 + g*8;
    unsigned short u[8];
    #pragma unroll
    for (int e = 0; e < 8; ++e)
      u[e] = __bfloat16_as_ushort(__float2bfloat16(
          X[(((long)(b*T_ + t))*N_ + n0 + e)*FIN_ + f]));
    *(uint4*)(XTf + ((long)t*CGSZ + ((long)kb*64 + l)*8)) = *(uint4*)u;
  } else {
    int flat = (blockIdx.x - 768)*256 + threadIdx.x;  // 0..32767
    int l = flat & 63, kb = (flat >> 6) & 255, b = flat >> 14;
    int lid = l & 15, g = l >> 4;
    int n0 = kb*32 + g*8;
    unsigned short u[8];
    #pragma unroll
    for (int e = 0; e < 8; ++e)
      u[e] = __bfloat16_as_ushort(__float2bfloat16(
          H[((long)b*N_ + n0 + e)*HID_ + lid]));
    *(uint4*)(hTf + ((long)b*CGSZ + ((long)kb*64 + l)*8)) = *(uint4*)u;
  }
}

// ---------------- MFMA core (baseline: normal loads; A allocates in L3) ----------------
__device__ __forceinline__ void mm_core32(
    const __hip_bfloat16* __restrict__ Lp,
    const __hip_bfloat16* __restrict__ B0f,
    const __hip_bfloat16* __restrict__ B1f,
    const __hip_bfloat16* __restrict__ B2f,
    float (*red)[2][3][64][4], int blk, int w, int lane)
{
  const int kb0 = w*32;
  const s8v* A0 = (const s8v*)(const void*)Lp + ((long)(blk*2+0)*256 + kb0)*64 + lane;
  const s8v* A1 = (const s8v*)(const void*)Lp + ((long)(blk*2+1)*256 + kb0)*64 + lane;
  const s8v* P0 = (const s8v*)(const void*)B0f + (long)kb0*64 + lane;
  const s8v* P1 = (const s8v*)(const void*)B1f + (long)kb0*64 + lane;
  const s8v* P2 = (const s8v*)(const void*)B2f + (long)kb0*64 + lane;
  f4v a00={0.f,0.f,0.f,0.f}, a01={0.f,0.f,0.f,0.f}, a02={0.f,0.f,0.f,0.f};
  f4v a10={0.f,0.f,0.f,0.f}, a11={0.f,0.f,0.f,0.f}, a12={0.f,0.f,0.f,0.f};
  #pragma unroll 4
  for (int kk = 0; kk < 32; ++kk){
    s8v a0 = A0[(long)kk*64];
    s8v a1 = A1[(long)kk*64];
    s8v b0 = P0[(long)kk*64];
    s8v b1 = P1[(long)kk*64];
    s8v b2 = P2[(long)kk*64];
    a00 = __builtin_amdgcn_mfma_f32_16x16x32_bf16(a0,b0,a00,0,0,0);
    a01 = __builtin_amdgcn_mfma_f32_16x16x32_bf16(a0,b1,a01,0,0,0);
    a02 = __builtin_amdgcn_mfma_f32_16x16x32_bf16(a0,b2,a02,0,0,0);
    a10 = __builtin_amdgcn_mfma_f32_16x16x32_bf16(a1,b0,a10,0,0,0);
    a11 = __builtin_amdgcn_mfma_f32_16x16x32_bf16(a1,b1,a11,0,0,0);
    a12 = __builtin_amdgcn_mfma_f32_16x16x32_bf16(a1,b2,a12,0,0,0);
  }
  *(f4v*)&red[w][0][0][lane][0] = a00;
  *(f4v*)&red[w][0][1][lane][0] = a01;
  *(f4v*)&red[w][0][2][lane][0] = a02;
  *(f4v*)&red[w][1][0][lane][0] = a10;
  *(f4v*)&red[w][1][1][lane][0] = a11;
  *(f4v*)&red[w][1][2][lane][0] = a12;
}

// ---------------- MFMA core variant: nontemporal A (reads L3 w/o polluting L2) ----------------
__device__ __forceinline__ void mm_core32_nt(
    const __hip_bfloat16* __restrict__ Lp,
    const __hip_bfloat16* __restrict__ B0f,
    const __hip_bfloat16* __restrict__ B1f,
    const __hip_bfloat16* __restrict__ B2f,
    float (*red)[2][3][64][4], int blk, int w, int lane)
{
  const int kb0 = w*32;
  const s8v* A0 = (const s8v*)(const void*)Lp + ((long)(blk*2+0)*256 + kb0)*64 + lane;
  const s8v* A1 = (const s8v*)(const void*)Lp + ((long)(blk*2+1)*256 + kb0)*64 + lane;
  const s8v* P0 = (const s8v*)(const void*)B0f + (long)kb0*64 + lane;
  const s8v* P1 = (const s8v*)(const void*)B1f + (long)kb0*64 + lane;
  const s8v* P2 = (const s8v*)(const void*)B2f + (long)kb0*64 + lane;
  f4v a00={0.f,0.f,0.f,0.f}, a01={0.f,0.f,0.f,0.f}, a02={0.f,0.f,0.f,0.f};
  f4v a10={0.f,0.f,0.f,0.f}, a11={0.f,0.f,0.f,0.f}, a12={0.f,0.f,0.f,0.f};
  #pragma unroll 4
  for (int kk = 0; kk < 32; ++kk){
    s8v a0 = __builtin_nontemporal_load(A0 + (long)kk*64);
    s8v a1 = __builtin_nontemporal_load(A1 + (long)kk*64);
    s8v b0 = P0[(long)kk*64];
    s8v b1 = P1[(long)kk*64];
    s8v b2 = P2[(long)kk*64];
    a00 = __builtin_amdgcn_mfma_f32_16x16x32_bf16(a0,b0,a00,0,0,0);
    a01 = __builtin_amdgcn_mfma_f32_16x16x32_bf16(a0,b1,a01,0,0,0);
    a02 = __builtin_amdgcn_mfma_f32_16x16x32_bf16(a0,b2,a02,0,0,0);
    a10 = __builtin_amdgcn_mfma_f32_16x16x32_bf16(a1,b0,a10,0,0,0);
    a11 = __builtin_amdgcn_mfma_f32_16x16x32_bf16(a1,b1,a11,0,0,0);
    a12 = __builtin_amdgcn_mfma_f32_16x16x32_bf16(a1,b2,a12,0,0,0);
  }
  *(f4v*)&red[w][0][0][lane][0] = a00;
  *(f4v*)&red[w][0][1][lane][0] = a01;
  *(f4v*)&red[w][0][2][lane][0] = a02;
  *(f4v*)&red[w][1][0][lane][0] = a10;
  *(f4v*)&red[w][1][1][lane][0] = a11;
  *(f4v*)&red[w][1][2][lane][0] = a12;
}

// ---------------- pass 1: [u(32) | p(16)] = L @ [h | x_t]  (+ bf16 frag out) ----------------
__global__ __launch_bounds__(512) void mm_pass1_kernel(
    const __hip_bfloat16* __restrict__ Lp,
    const __hip_bfloat16* __restrict__ hTf,
    const __hip_bfloat16* __restrict__ XTft,
    __hip_bfloat16* __restrict__ y1f,
    float* __restrict__ u_, float* __restrict__ p_)
{
  __shared__ float red[8][2][3][64][4];   // 49152 B
  const int tid = threadIdx.x, w = tid >> 6, lane = tid & 63, blk = blockIdx.x;
  mm_core32(Lp, hTf, hTf + CGSZ, XTft, red, blk, w, lane);
  __syncthreads();
  for (int v = tid; v < 1536; v += 512){
    int rtl = (v >= 768) ? 1 : 0;
    int rem = v - rtl*768;
    int cgI = rem >> 8, r255 = rem & 255;
    int lid = r255 & 15, r = r255 >> 4;
    int g = r >> 2, j = r & 3;
    float s = 0.f;
    #pragma unroll
    for (int ww = 0; ww < 8; ++ww) s += red[ww][rtl][cgI][g*16 + lid][j];
    int n = blk*32 + rtl*16 + r;
    long o = (((long)cgI*256 + (n>>5))*64 + ((n>>3)&3)*16 + lid)*8 + (n&7);
    y1f[o] = __float2bfloat16(s);
    if (cgI < 2) u_[((long)cgI*N_ + n)*HID_ + lid] = s;
    else         p_[((long)(lid>>3)*N_ + n)*FIN_ + (lid&7)] = s;
  }
}

// ---------------- pass 2 + fused gates (nontemporal-A core) ----------------
__global__ __launch_bounds__(512) void mm_pass2_gate_kernel(
    const __hip_bfloat16* __restrict__ Lp,
    const __hip_bfloat16* __restrict__ y1f,
    const float* __restrict__ X,
    const float* __restrict__ H0, const float* __restrict__ C0,
    const float* __restrict__ Wx, const float* __restrict__ Wh,
    const float* __restrict__ bx, const float* __restrict__ bh,
    const float* __restrict__ wc, const float* __restrict__ bg,
    const float* __restrict__ u_, const float* __restrict__ p_,
    float* __restrict__ out, float* __restrict__ hs, float* __restrict__ cs,
    __hip_bfloat16* __restrict__ hTf, int t)
{
  __shared__ float red[8][2][3][64][4];   // 49152 B
  __shared__ float uv[48][32];            //  6144 B  [col][row-in-block]
  __shared__ float wlds[4848];            // 19392 B
  const int tid = threadIdx.x, w = tid >> 6, lane = tid & 63, blk = blockIdx.x;
  mm_core32_nt(Lp, y1f, y1f + CGSZ, y1f + 2*CGSZ, red, blk, w, lane);
  // stage this timestep's gate weights (independent of red)
  for (int i = tid; i < 1536; i += 512) wlds[i] = Wx[(long)t*1536 + i];
  for (int i = tid; i < 3072; i += 512) wlds[1536 + i] = Wh[(long)t*3072 + i];
  if (tid < 64){
    wlds[4608 + tid] = bx[t*64 + tid];
    wlds[4672 + tid] = bh[t*64 + tid];
    wlds[4736 + tid] = bg[t*64 + tid];
  }
  if (tid < 48) wlds[4800 + tid] = wc[t*48 + tid];
  __syncthreads();
  for (int v = tid; v < 1536; v += 512){
    int rtl = (v >= 768) ? 1 : 0;
    int rem = v - rtl*768;
    int cgI = rem >> 8, r255 = rem & 255;
    int lid = r255 & 15, r = r255 >> 4;
    int g = r >> 2, j = r & 3;
    float s = 0.f;
    #pragma unroll
    for (int ww = 0; ww < 8; ++ww) s += red[ww][rtl][cgI][g*16 + lid][j];
    uv[cgI*16 + lid][rtl*16 + r] = s;
  }
  __syncthreads();

  // gates: 1024 items (2 batch x 32 rows x 16 hid) over 512 threads
  #pragma unroll
  for (int it = 0; it < 2; ++it){
    int item = it*512 + tid;
    int gb = item >> 9, rr = (item >> 4) & 31, gh = item & 15;
    int n_g = blk*32 + rr;
    const float* xp = X + (((long)(gb*T_ + t))*N_ + n_g)*FIN_;
    const float* hp = (t==0) ? (H0 + ((long)gb*N_ + n_g)*HID_)
                             : (hs + (((long)(t-1)*B_ + gb)*N_ + n_g)*HID_);
    const float* cp = (t==0) ? (C0 + ((long)gb*N_ + n_g)*HID_)
                             : (cs + (((long)(t-1)*B_ + gb)*N_ + n_g)*HID_);
    const float* up = u_ + ((long)gb*N_ + n_g)*HID_;
    const float* pp = p_ + ((long)gb*N_ + n_g)*FIN_;

    float pre0 = wlds[4608 +  0 + gh] + wlds[4672 +  0 + gh] + wlds[4736 +  0 + gh];
    float pre1 = wlds[4608 + 16 + gh] + wlds[4672 + 16 + gh] + wlds[4736 + 16 + gh];
    float pre2 = wlds[4608 + 32 + gh] + wlds[4672 + 32 + gh] + wlds[4736 + 32 + gh];
    float pre3 = wlds[4608 + 48 + gh] + wlds[4672 + 48 + gh] + wlds[4736 + 48 + gh];
    #pragma unroll
    for (int f = 0; f < 8; ++f){
      float t0 = xp[f];
      float t1 = pp[f];
      float t2 = 2.f*uv[32 + gb*8 + f][rr] - t0;
      pre0 += t0*wlds[((0*3+0)*8+f)*16+gh] + t1*wlds[((0*3+1)*8+f)*16+gh] + t2*wlds[((0*3+2)*8+f)*16+gh];
      pre1 += t0*wlds[((1*3+0)*8+f)*16+gh] + t1*wlds[((1*3+1)*8+f)*16+gh] + t2*wlds[((1*3+2)*8+f)*16+gh];
      pre2 += t0*wlds[((2*3+0)*8+f)*16+gh] + t1*wlds[((2*3+1)*8+f)*16+gh] + t2*wlds[((2*3+2)*8+f)*16+gh];
      pre3 += t0*wlds[((3*3+0)*8+f)*16+gh] + t1*wlds[((3*3+1)*8+f)*16+gh] + t2*wlds[((3*3+2)*8+f)*16+gh];
    }
    #pragma unroll
    for (int j = 0; j < 16; ++j){
      float t0 = hp[j];
      float t1 = up[j];
      float t2 = 2.f*uv[gb*16 + j][rr] - t0;
      pre0 += t0*wlds[1536+((0*3+0)*16+j)*16+gh] + t1*wlds[1536+((0*3+1)*16+j)*16+gh] + t2*wlds[1536+((0*3+2)*16+j)*16+gh];
      pre1 += t0*wlds[1536+((1*3+0)*16+j)*16+gh] + t1*wlds[1536+((1*3+1)*16+j)*16+gh] + t2*wlds[1536+((1*3+2)*16+j)*16+gh];
      pre2 += t0*wlds[1536+((2*3+0)*16+j)*16+gh] + t1*wlds[1536+((2*3+1)*16+j)*16+gh] + t2*wlds[1536+((2*3+2)*16+j)*16+gh];
      pre3 += t0*wlds[1536+((3*3+0)*16+j)*16+gh] + t1*wlds[1536+((3*3+1)*16+j)*16+gh] + t2*wlds[1536+((3*3+2)*16+j)*16+gh];
    }
    float cc = cp[gh];
    float ig = sigmoidf_(pre0 + wlds[4800 +  0 + gh]*cc);
    float fg = sigmoidf_(pre1 + wlds[4800 + 16 + gh]*cc);
    float cnew = fg*cc + ig*tanhf(pre2);
    float og = sigmoidf_(pre3 + wlds[4800 + 32 + gh]*cnew);
    float hn = og*tanhf(cnew);
    hs [(((long)t*B_ + gb)*N_ + n_g)*HID_ + gh] = hn;
    cs [(((long)t*B_ + gb)*N_ + n_g)*HID_ + gh] = cnew;
    out[(((long)gb*T_ + t)*N_ + n_g)*HID_ + gh] = hn;
    const int kb = n_g >> 5, gg = (n_g >> 3) & 3, e = n_g & 7;
    hTf[(((long)gb*256 + kb)*64 + gg*16 + gh)*8 + e] = __float2bfloat16(hn);
  }
}

extern "C" void kernel_launch(void* const* d_in, const int* in_sizes, int n_in,
                              void* d_out, int out_size, void* d_ws, size_t ws_size,
                              hipStream_t stream)
{
  const float* X  = (const float*)d_in[0];
  const float* L  = (const float*)d_in[1];
  const float* H  = (const float*)d_in[2];
  const float* C  = (const float*)d_in[3];
  const float* Wx = (const float*)d_in[4];
  const float* Wh = (const float*)d_in[5];
  const float* bx = (const float*)d_in[6];
  const float* bh = (const float*)d_in[7];
  const float* wc = (const float*)d_in[8];
  const float* bg = (const float*)d_in[9];

  float* out = (float*)d_out;
  float* hs  = out + (long)B_*T_*N_*HID_;
  float* cs  = hs  + (long)T_*B_*N_*HID_;

  const size_t NEEDED = 140247040;
  if (ws_size < NEEDED) return;
  char* ws = (char*)d_ws;
  __hip_bfloat16* Lp  = (__hip_bfloat16*)(ws);                   // 128 MiB frag-major L
  __hip_bfloat16* XTf = (__hip_bfloat16*)(ws + 134217728);       // 3 MiB   [12][CGSZ]
  __hip_bfloat16* hTf = (__hip_bfloat16*)(ws + 137363456);       // 512 KiB [2][CGSZ]
  __hip_bfloat16* y1f = (__hip_bfloat16*)(ws + 137887744);       // 768 KiB [3][CGSZ]
  float* u_ = (float*)(ws + 138674176);                          // 1 MiB   [2][8192][16]
  float* p_ = (float*)(ws + 139722752);                          // 512 KiB [2][8192][8]

  build_Lp_kernel<<<dim3(32,512), 256, 0, stream>>>(L, Lp);
  pack_xh_kernel <<<896, 256, 0, stream>>>(X, H, XTf, hTf);

  for (int t = 0; t < T_; ++t){
    // pass1: normal A loads (allocate/refresh Lp in L3)
    mm_pass1_kernel<<<256, 512, 0, stream>>>(Lp, hTf, XTf + (long)t*CGSZ,
                                             y1f, u_, p_);
    // pass2: nontemporal A loads (consume warm L3, keep B resident in L2)
    mm_pass2_gate_kernel<<<256, 512, 0, stream>>>(Lp, y1f, X, H, C,
                                                  Wx, Wh, bx, bh, wc, bg,
                                                  u_, p_, out, hs, cs, hTf, t);
  }
}

// Round 12
// 1083.501 us; speedup vs baseline: 2.5102x; 1.1114x over previous
//
#include <hip/hip_runtime.h>
#include <hip/hip_bf16.h>

#define N_ 8192
#define T_ 12
#define B_ 2
#define FIN_ 8
#define HID_ 16
#define CGSZ 131072   // one column-group (16 cols) frag block: 256 kb * 64 lanes * 8 elems

typedef short s8v __attribute__((ext_vector_type(8)));
typedef float f4v __attribute__((ext_vector_type(4)));

__device__ __forceinline__ float sigmoidf_(float x){ return 1.f/(1.f + __expf(-x)); }

#define MFMA16(a,b,c) __builtin_amdgcn_mfma_f32_16x16x32_bf16(a,b,c,0,0,0)

// ---------------- prep: L fp32 -> bf16 fragment-major ----------------
// Lp[((rt*256 + kb)*64 + l)*8 + e] = bf16( L[rt*16 + (l&15)][kb*32 + (l>>4)*8 + e] )
__global__ __launch_bounds__(256) void build_Lp_kernel(const float* __restrict__ L,
                                                       __hip_bfloat16* __restrict__ Lp){
  __shared__ unsigned short tile[16][264];
  const int cb = blockIdx.x;   // 0..31
  const int rt = blockIdx.y;   // 0..511
  const int tid = threadIdx.x;
  #pragma unroll
  for (int i = 0; i < 4; ++i){
    int flat = i*256 + tid;
    int r  = flat >> 6;
    int c4 = flat & 63;
    float4 v = *(const float4*)(L + (long)(rt*16 + r)*N_ + cb*256 + c4*4);
    tile[r][c4*4+0] = __bfloat16_as_ushort(__float2bfloat16(v.x));
    tile[r][c4*4+1] = __bfloat16_as_ushort(__float2bfloat16(v.y));
    tile[r][c4*4+2] = __bfloat16_as_ushort(__float2bfloat16(v.z));
    tile[r][c4*4+3] = __bfloat16_as_ushort(__float2bfloat16(v.w));
  }
  __syncthreads();
  #pragma unroll
  for (int j = 0; j < 2; ++j){
    int flat = j*256 + tid;
    int kbl = flat >> 6;
    int l   = flat & 63;
    int lid = l & 15, g = l >> 4;
    uint4 frag = *(const uint4*)&tile[lid][kbl*32 + g*8];
    *(uint4*)(Lp + (((long)rt*256 + cb*8 + kbl)*64 + l)*8) = frag;
  }
}

// ---------------- prep: X (all t) and h0 -> bf16 frag-major (merged) ----------------
__global__ __launch_bounds__(256) void pack_xh_kernel(const float* __restrict__ X,
                                                      const float* __restrict__ H,
                                                      __hip_bfloat16* __restrict__ XTf,
                                                      __hip_bfloat16* __restrict__ hTf){
  if (blockIdx.x < 768){
    const int t = blockIdx.x >> 6;
    int flat = (blockIdx.x & 63)*256 + threadIdx.x;   // 0..16383
    int l = flat & 63, kb = flat >> 6;
    int lid = l & 15, g = l >> 4;
    int b = lid >> 3, f = lid & 7;
    int n0 = kb*32 + g*8;
    unsigned short u[8];
    #pragma unroll
    for (int e = 0; e < 8; ++e)
      u[e] = __bfloat16_as_ushort(__float2bfloat16(
          X[(((long)(b*T_ + t))*N_ + n0 + e)*FIN_ + f]));
    *(uint4*)(XTf + ((long)t*CGSZ + ((long)kb*64 + l)*8)) = *(uint4*)u;
  } else {
    int flat = (blockIdx.x - 768)*256 + threadIdx.x;  // 0..32767
    int l = flat & 63, kb = (flat >> 6) & 255, b = flat >> 14;
    int lid = l & 15, g = l >> 4;
    int n0 = kb*32 + g*8;
    unsigned short u[8];
    #pragma unroll
    for (int e = 0; e < 8; ++e)
      u[e] = __bfloat16_as_ushort(__float2bfloat16(
          H[((long)b*N_ + n0 + e)*HID_ + lid]));
    *(uint4*)(hTf + ((long)b*CGSZ + ((long)kb*64 + l)*8)) = *(uint4*)u;
  }
}

// ---------------- MFMA core: software-pipelined, prefetch distance 2 ----------------
// Named register sets keep >=10 loads in flight per wave (R10 counters showed the
// compiler's default schedule holds only 5: VGPR_Count=40 -> ~50% memory duty cycle).
__device__ __forceinline__ void mm_core32(
    const __hip_bfloat16* __restrict__ Lp,
    const __hip_bfloat16* __restrict__ B0f,
    const __hip_bfloat16* __restrict__ B1f,
    const __hip_bfloat16* __restrict__ B2f,
    float (*red)[2][3][64][4], int blk, int w, int lane)
{
  const int kb0 = w*32;
  const s8v* A0 = (const s8v*)(const void*)Lp + ((long)(blk*2+0)*256 + kb0)*64 + lane;
  const s8v* A1 = (const s8v*)(const void*)Lp + ((long)(blk*2+1)*256 + kb0)*64 + lane;
  const s8v* P0 = (const s8v*)(const void*)B0f + (long)kb0*64 + lane;
  const s8v* P1 = (const s8v*)(const void*)B1f + (long)kb0*64 + lane;
  const s8v* P2 = (const s8v*)(const void*)B2f + (long)kb0*64 + lane;
  f4v a00={0.f,0.f,0.f,0.f}, a01={0.f,0.f,0.f,0.f}, a02={0.f,0.f,0.f,0.f};
  f4v a10={0.f,0.f,0.f,0.f}, a11={0.f,0.f,0.f,0.f}, a12={0.f,0.f,0.f,0.f};

  // prologue: stages kk=0 (X set) and kk=1 (Y set)
  s8v a0x = A0[0],  a1x = A1[0],  b0x = P0[0],  b1x = P1[0],  b2x = P2[0];
  s8v a0y = A0[64], a1y = A1[64], b0y = P0[64], b1y = P1[64], b2y = P2[64];

  #pragma unroll 2
  for (int kk = 0; kk < 30; ++kk){
    // issue stage kk+2 while consuming stage kk
    s8v a0n = A0[(long)(kk+2)*64];
    s8v a1n = A1[(long)(kk+2)*64];
    s8v b0n = P0[(long)(kk+2)*64];
    s8v b1n = P1[(long)(kk+2)*64];
    s8v b2n = P2[(long)(kk+2)*64];
    a00 = MFMA16(a0x,b0x,a00); a01 = MFMA16(a0x,b1x,a01); a02 = MFMA16(a0x,b2x,a02);
    a10 = MFMA16(a1x,b0x,a10); a11 = MFMA16(a1x,b1x,a11); a12 = MFMA16(a1x,b2x,a12);
    a0x=a0y; a1x=a1y; b0x=b0y; b1x=b1y; b2x=b2y;
    a0y=a0n; a1y=a1n; b0y=b0n; b1y=b1n; b2y=b2n;
  }
  // epilogue: stages 30, 31
  a00 = MFMA16(a0x,b0x,a00); a01 = MFMA16(a0x,b1x,a01); a02 = MFMA16(a0x,b2x,a02);
  a10 = MFMA16(a1x,b0x,a10); a11 = MFMA16(a1x,b1x,a11); a12 = MFMA16(a1x,b2x,a12);
  a00 = MFMA16(a0y,b0y,a00); a01 = MFMA16(a0y,b1y,a01); a02 = MFMA16(a0y,b2y,a02);
  a10 = MFMA16(a1y,b0y,a10); a11 = MFMA16(a1y,b1y,a11); a12 = MFMA16(a1y,b2y,a12);

  *(f4v*)&red[w][0][0][lane][0] = a00;
  *(f4v*)&red[w][0][1][lane][0] = a01;
  *(f4v*)&red[w][0][2][lane][0] = a02;
  *(f4v*)&red[w][1][0][lane][0] = a10;
  *(f4v*)&red[w][1][1][lane][0] = a11;
  *(f4v*)&red[w][1][2][lane][0] = a12;
}

// ---------------- pass 1: [u(32) | p(16)] = L @ [h | x_t]  (+ bf16 frag out) ----------------
__global__ __launch_bounds__(512) void mm_pass1_kernel(
    const __hip_bfloat16* __restrict__ Lp,
    const __hip_bfloat16* __restrict__ hTf,
    const __hip_bfloat16* __restrict__ XTft,
    __hip_bfloat16* __restrict__ y1f,
    float* __restrict__ u_, float* __restrict__ p_)
{
  __shared__ float red[8][2][3][64][4];   // 49152 B
  const int tid = threadIdx.x, w = tid >> 6, lane = tid & 63, blk = blockIdx.x;
  mm_core32(Lp, hTf, hTf + CGSZ, XTft, red, blk, w, lane);
  __syncthreads();
  for (int v = tid; v < 1536; v += 512){
    int rtl = (v >= 768) ? 1 : 0;
    int rem = v - rtl*768;
    int cgI = rem >> 8, r255 = rem & 255;
    int lid = r255 & 15, r = r255 >> 4;
    int g = r >> 2, j = r & 3;
    float s = 0.f;
    #pragma unroll
    for (int ww = 0; ww < 8; ++ww) s += red[ww][rtl][cgI][g*16 + lid][j];
    int n = blk*32 + rtl*16 + r;
    long o = (((long)cgI*256 + (n>>5))*64 + ((n>>3)&3)*16 + lid)*8 + (n&7);
    y1f[o] = __float2bfloat16(s);
    if (cgI < 2) u_[((long)cgI*N_ + n)*HID_ + lid] = s;
    else         p_[((long)(lid>>3)*N_ + n)*FIN_ + (lid&7)] = s;
  }
}

// ---------------- pass 2 + fused gates ----------------
__global__ __launch_bounds__(512) void mm_pass2_gate_kernel(
    const __hip_bfloat16* __restrict__ Lp,
    const __hip_bfloat16* __restrict__ y1f,
    const float* __restrict__ X,
    const float* __restrict__ H0, const float* __restrict__ C0,
    const float* __restrict__ Wx, const float* __restrict__ Wh,
    const float* __restrict__ bx, const float* __restrict__ bh,
    const float* __restrict__ wc, const float* __restrict__ bg,
    const float* __restrict__ u_, const float* __restrict__ p_,
    float* __restrict__ out, float* __restrict__ hs, float* __restrict__ cs,
    __hip_bfloat16* __restrict__ hTf, int t)
{
  __shared__ float red[8][2][3][64][4];   // 49152 B
  __shared__ float uv[48][32];            //  6144 B  [col][row-in-block]
  __shared__ float wlds[4848];            // 19392 B
  const int tid = threadIdx.x, w = tid >> 6, lane = tid & 63, blk = blockIdx.x;
  mm_core32(Lp, y1f, y1f + CGSZ, y1f + 2*CGSZ, red, blk, w, lane);
  // stage this timestep's gate weights (independent of red)
  for (int i = tid; i < 1536; i += 512) wlds[i] = Wx[(long)t*1536 + i];
  for (int i = tid; i < 3072; i += 512) wlds[1536 + i] = Wh[(long)t*3072 + i];
  if (tid < 64){
    wlds[4608 + tid] = bx[t*64 + tid];
    wlds[4672 + tid] = bh[t*64 + tid];
    wlds[4736 + tid] = bg[t*64 + tid];
  }
  if (tid < 48) wlds[4800 + tid] = wc[t*48 + tid];
  __syncthreads();
  for (int v = tid; v < 1536; v += 512){
    int rtl = (v >= 768) ? 1 : 0;
    int rem = v - rtl*768;
    int cgI = rem >> 8, r255 = rem & 255;
    int lid = r255 & 15, r = r255 >> 4;
    int g = r >> 2, j = r & 3;
    float s = 0.f;
    #pragma unroll
    for (int ww = 0; ww < 8; ++ww) s += red[ww][rtl][cgI][g*16 + lid][j];
    uv[cgI*16 + lid][rtl*16 + r] = s;
  }
  __syncthreads();

  // gates: 1024 items (2 batch x 32 rows x 16 hid) over 512 threads
  #pragma unroll
  for (int it = 0; it < 2; ++it){
    int item = it*512 + tid;
    int gb = item >> 9, rr = (item >> 4) & 31, gh = item & 15;
    int n_g = blk*32 + rr;
    const float* xp = X + (((long)(gb*T_ + t))*N_ + n_g)*FIN_;
    const float* hp = (t==0) ? (H0 + ((long)gb*N_ + n_g)*HID_)
                             : (hs + (((long)(t-1)*B_ + gb)*N_ + n_g)*HID_);
    const float* cp = (t==0) ? (C0 + ((long)gb*N_ + n_g)*HID_)
                             : (cs + (((long)(t-1)*B_ + gb)*N_ + n_g)*HID_);
    const float* up = u_ + ((long)gb*N_ + n_g)*HID_;
    const float* pp = p_ + ((long)gb*N_ + n_g)*FIN_;

    float pre0 = wlds[4608 +  0 + gh] + wlds[4672 +  0 + gh] + wlds[4736 +  0 + gh];
    float pre1 = wlds[4608 + 16 + gh] + wlds[4672 + 16 + gh] + wlds[4736 + 16 + gh];
    float pre2 = wlds[4608 + 32 + gh] + wlds[4672 + 32 + gh] + wlds[4736 + 32 + gh];
    float pre3 = wlds[4608 + 48 + gh] + wlds[4672 + 48 + gh] + wlds[4736 + 48 + gh];
    #pragma unroll
    for (int f = 0; f < 8; ++f){
      float t0 = xp[f];
      float t1 = pp[f];
      float t2 = 2.f*uv[32 + gb*8 + f][rr] - t0;
      pre0 += t0*wlds[((0*3+0)*8+f)*16+gh] + t1*wlds[((0*3+1)*8+f)*16+gh] + t2*wlds[((0*3+2)*8+f)*16+gh];
      pre1 += t0*wlds[((1*3+0)*8+f)*16+gh] + t1*wlds[((1*3+1)*8+f)*16+gh] + t2*wlds[((1*3+2)*8+f)*16+gh];
      pre2 += t0*wlds[((2*3+0)*8+f)*16+gh] + t1*wlds[((2*3+1)*8+f)*16+gh] + t2*wlds[((2*3+2)*8+f)*16+gh];
      pre3 += t0*wlds[((3*3+0)*8+f)*16+gh] + t1*wlds[((3*3+1)*8+f)*16+gh] + t2*wlds[((3*3+2)*8+f)*16+gh];
    }
    #pragma unroll
    for (int j = 0; j < 16; ++j){
      float t0 = hp[j];
      float t1 = up[j];
      float t2 = 2.f*uv[gb*16 + j][rr] - t0;
      pre0 += t0*wlds[1536+((0*3+0)*16+j)*16+gh] + t1*wlds[1536+((0*3+1)*16+j)*16+gh] + t2*wlds[1536+((0*3+2)*16+j)*16+gh];
      pre1 += t0*wlds[1536+((1*3+0)*16+j)*16+gh] + t1*wlds[1536+((1*3+1)*16+j)*16+gh] + t2*wlds[1536+((1*3+2)*16+j)*16+gh];
      pre2 += t0*wlds[1536+((2*3+0)*16+j)*16+gh] + t1*wlds[1536+((2*3+1)*16+j)*16+gh] + t2*wlds[1536+((2*3+2)*16+j)*16+gh];
      pre3 += t0*wlds[1536+((3*3+0)*16+j)*16+gh] + t1*wlds[1536+((3*3+1)*16+j)*16+gh] + t2*wlds[1536+((3*3+2)*16+j)*16+gh];
    }
    float cc = cp[gh];
    float ig = sigmoidf_(pre0 + wlds[4800 +  0 + gh]*cc);
    float fg = sigmoidf_(pre1 + wlds[4800 + 16 + gh]*cc);
    float cnew = fg*cc + ig*tanhf(pre2);
    float og = sigmoidf_(pre3 + wlds[4800 + 32 + gh]*cnew);
    float hn = og*tanhf(cnew);
    hs [(((long)t*B_ + gb)*N_ + n_g)*HID_ + gh] = hn;
    cs [(((long)t*B_ + gb)*N_ + n_g)*HID_ + gh] = cnew;
    out[(((long)gb*T_ + t)*N_ + n_g)*HID_ + gh] = hn;
    const int kb = n_g >> 5, gg = (n_g >> 3) & 3, e = n_g & 7;
    hTf[(((long)gb*256 + kb)*64 + gg*16 + gh)*8 + e] = __float2bfloat16(hn);
  }
}

extern "C" void kernel_launch(void* const* d_in, const int* in_sizes, int n_in,
                              void* d_out, int out_size, void* d_ws, size_t ws_size,
                              hipStream_t stream)
{
  const float* X  = (const float*)d_in[0];
  const float* L  = (const float*)d_in[1];
  const float* H  = (const float*)d_in[2];
  const float* C  = (const float*)d_in[3];
  const float* Wx = (const float*)d_in[4];
  const float* Wh = (const float*)d_in[5];
  const float* bx = (const float*)d_in[6];
  const float* bh = (const float*)d_in[7];
  const float* wc = (const float*)d_in[8];
  const float* bg = (const float*)d_in[9];

  float* out = (float*)d_out;
  float* hs  = out + (long)B_*T_*N_*HID_;
  float* cs  = hs  + (long)T_*B_*N_*HID_;

  const size_t NEEDED = 140247040;
  if (ws_size < NEEDED) return;
  char* ws = (char*)d_ws;
  __hip_bfloat16* Lp  = (__hip_bfloat16*)(ws);                   // 128 MiB frag-major L
  __hip_bfloat16* XTf = (__hip_bfloat16*)(ws + 134217728);       // 3 MiB   [12][CGSZ]
  __hip_bfloat16* hTf = (__hip_bfloat16*)(ws + 137363456);       // 512 KiB [2][CGSZ]
  __hip_bfloat16* y1f = (__hip_bfloat16*)(ws + 137887744);       // 768 KiB [3][CGSZ]
  float* u_ = (float*)(ws + 138674176);                          // 1 MiB   [2][8192][16]
  float* p_ = (float*)(ws + 139722752);                          // 512 KiB [2][8192][8]

  build_Lp_kernel<<<dim3(32,512), 256, 0, stream>>>(L, Lp);
  pack_xh_kernel <<<896, 256, 0, stream>>>(X, H, XTf, hTf);

  for (int t = 0; t < T_; ++t){
    mm_pass1_kernel<<<256, 512, 0, stream>>>(Lp, hTf, XTf + (long)t*CGSZ,
                                             y1f, u_, p_);
    mm_pass2_gate_kernel<<<256, 512, 0, stream>>>(Lp, y1f, X, H, C,
                                                  Wx, Wh, bx, bh, wc, bg,
                                                  u_, p_, out, hs, cs, hTf, t);
  }
}